// Round 1
// baseline (2682.615 us; speedup 1.0000x reference)
//
#include <hip/hip_runtime.h>
#include <hip/hip_bf16.h>
#include <math.h>

#define B_ 4
#define S_ 2048
#define D_ 512
#define H_ 8
#define DK_ 64
#define DFF_ 2048
#define NEG_ (-1.0e9f)
#define EPS_ 1e-6f

// ---------------------------------------------------------------------------
// Mask canonicalization: jnp.bool_ may arrive as u8 (1B) or i32/f32 (4B).
// Detect layout from first 8KB (safe under either), write int32 mask to ws.
// ---------------------------------------------------------------------------
__global__ void mask_canon_kernel(const unsigned char* __restrict__ mraw,
                                  int* __restrict__ cm) {
    __shared__ int s_bad;
    int tid = threadIdx.x;
    if (tid == 0) s_bad = 0;
    __syncthreads();
    const unsigned int* w = (const unsigned int*)mraw;
    int bad = 0;
    for (int i = tid; i < (B_ * S_) / 4; i += 256) {  // first 8KB as words
        unsigned int v = w[i];
        if (!(v == 0u || v == 1u || v == 0x3F800000u)) bad = 1;
    }
    if (bad) atomicOr(&s_bad, 1);
    __syncthreads();
    if (s_bad) {  // u8 layout
        for (int i = tid; i < B_ * S_; i += 256) cm[i] = mraw[i] ? 1 : 0;
    } else {      // 4-byte layout (i32 0/1 or f32 0.0/1.0 -- both: word != 0)
        for (int i = tid; i < B_ * S_; i += 256) cm[i] = w[i] ? 1 : 0;
    }
}

// ---------------------------------------------------------------------------
// GEMM: C[M,N] = A[M,K] @ W[N,K]^T + bias, optional ReLU. 64x64 tile.
// ---------------------------------------------------------------------------
__global__ __launch_bounds__(256) void gemm_bias_kernel(
    const float* __restrict__ A, const float* __restrict__ W,
    const float* __restrict__ bias, float* __restrict__ C,
    int M, int N, int K, int relu)
{
    __shared__ float As[64][17];
    __shared__ float Ws[64][17];
    int tid = threadIdx.x;
    int tx = tid & 15, ty = tid >> 4;
    int m0 = blockIdx.y * 64;
    int n0 = blockIdx.x * 64;
    float acc[4][4] = {};
    for (int k0 = 0; k0 < K; k0 += 16) {
        int idx = tid * 4;
        int r = idx >> 4;
        int c = idx & 15;
        float4 av = *reinterpret_cast<const float4*>(&A[(size_t)(m0 + r) * K + k0 + c]);
        As[r][c + 0] = av.x; As[r][c + 1] = av.y; As[r][c + 2] = av.z; As[r][c + 3] = av.w;
        float4 wv = *reinterpret_cast<const float4*>(&W[(size_t)(n0 + r) * K + k0 + c]);
        Ws[r][c + 0] = wv.x; Ws[r][c + 1] = wv.y; Ws[r][c + 2] = wv.z; Ws[r][c + 3] = wv.w;
        __syncthreads();
        #pragma unroll
        for (int kk = 0; kk < 16; ++kk) {
            float a[4], b[4];
            #pragma unroll
            for (int i = 0; i < 4; ++i) a[i] = As[ty * 4 + i][kk];
            #pragma unroll
            for (int j = 0; j < 4; ++j) b[j] = Ws[tx * 4 + j][kk];
            #pragma unroll
            for (int i = 0; i < 4; ++i)
                #pragma unroll
                for (int j = 0; j < 4; ++j)
                    acc[i][j] = fmaf(a[i], b[j], acc[i][j]);
        }
        __syncthreads();
    }
    #pragma unroll
    for (int i = 0; i < 4; ++i) {
        int m = m0 + ty * 4 + i;
        int n = n0 + tx * 4;
        float4 o;
        o.x = acc[i][0] + bias[n + 0];
        o.y = acc[i][1] + bias[n + 1];
        o.z = acc[i][2] + bias[n + 2];
        o.w = acc[i][3] + bias[n + 3];
        if (relu) {
            o.x = fmaxf(o.x, 0.f); o.y = fmaxf(o.y, 0.f);
            o.z = fmaxf(o.z, 0.f); o.w = fmaxf(o.w, 0.f);
        }
        *reinterpret_cast<float4*>(&C[(size_t)m * N + n]) = o;
    }
}

// ---------------------------------------------------------------------------
// Flash-style attention. Block = 256 threads = 32 q-rows x 8 threads/row.
// One block per (q-tile of 32, head, batch). Online softmax over k-tiles of 32.
// ---------------------------------------------------------------------------
__global__ __launch_bounds__(256) void attn_kernel(
    const float* __restrict__ Q, const float* __restrict__ Km,
    const float* __restrict__ V, const int* __restrict__ cmask,
    float* __restrict__ O)
{
    __shared__ float qs[32][65];
    __shared__ float ks[32][65];
    __shared__ float vs[32][65];
    __shared__ float Ps[32][33];
    __shared__ int ms[32];

    int tid = threadIdx.x;
    int row = tid >> 3;   // 0..31
    int col = tid & 7;    // 0..7
    int q0 = blockIdx.x * 32;
    int h = blockIdx.y;
    int b = blockIdx.z;

    const size_t base = ((size_t)b * S_) * D_ + (size_t)h * DK_;

    {   // load q tile: 32x64, 8 consecutive floats per thread
        int idx = tid * 8;
        int r = idx >> 6, c = idx & 63;
        const float* src = &Q[base + (size_t)(q0 + r) * D_ + c];
        float4 v0 = *reinterpret_cast<const float4*>(src);
        float4 v1 = *reinterpret_cast<const float4*>(src + 4);
        qs[r][c + 0] = v0.x; qs[r][c + 1] = v0.y; qs[r][c + 2] = v0.z; qs[r][c + 3] = v0.w;
        qs[r][c + 4] = v1.x; qs[r][c + 5] = v1.y; qs[r][c + 6] = v1.z; qs[r][c + 7] = v1.w;
    }

    float m_run = -INFINITY, l_run = 0.f;
    float o[8] = {};

    for (int k0 = 0; k0 < S_; k0 += 32) {
        __syncthreads();  // previous PV reads done before restage
        {
            int idx = tid * 8;
            int r = idx >> 6, c = idx & 63;
            const float* ksrc = &Km[base + (size_t)(k0 + r) * D_ + c];
            float4 a0 = *reinterpret_cast<const float4*>(ksrc);
            float4 a1 = *reinterpret_cast<const float4*>(ksrc + 4);
            ks[r][c + 0] = a0.x; ks[r][c + 1] = a0.y; ks[r][c + 2] = a0.z; ks[r][c + 3] = a0.w;
            ks[r][c + 4] = a1.x; ks[r][c + 5] = a1.y; ks[r][c + 6] = a1.z; ks[r][c + 7] = a1.w;
            const float* vsrc = &V[base + (size_t)(k0 + r) * D_ + c];
            float4 b0 = *reinterpret_cast<const float4*>(vsrc);
            float4 b1 = *reinterpret_cast<const float4*>(vsrc + 4);
            vs[r][c + 0] = b0.x; vs[r][c + 1] = b0.y; vs[r][c + 2] = b0.z; vs[r][c + 3] = b0.w;
            vs[r][c + 4] = b1.x; vs[r][c + 5] = b1.y; vs[r][c + 6] = b1.z; vs[r][c + 7] = b1.w;
        }
        if (tid < 32) ms[tid] = cmask[b * S_ + k0 + tid];
        __syncthreads();

        float s[4];
        #pragma unroll
        for (int ji = 0; ji < 4; ++ji) {
            int j = col + ji * 8;
            float acc = 0.f;
            #pragma unroll
            for (int d = 0; d < 64; ++d)
                acc = fmaf(qs[row][d], ks[j][d], acc);
            s[ji] = ms[j] ? NEG_ : acc * 0.125f;  // 1/sqrt(64)
        }
        float mt = fmaxf(fmaxf(s[0], s[1]), fmaxf(s[2], s[3]));
        mt = fmaxf(mt, __shfl_xor(mt, 1));
        mt = fmaxf(mt, __shfl_xor(mt, 2));
        mt = fmaxf(mt, __shfl_xor(mt, 4));
        float m_new = fmaxf(m_run, mt);
        float scale = expf(m_run - m_new);
        float psum = 0.f;
        #pragma unroll
        for (int ji = 0; ji < 4; ++ji) {
            float p = expf(s[ji] - m_new);
            Ps[row][col + ji * 8] = p;
            psum += p;
        }
        psum += __shfl_xor(psum, 1);
        psum += __shfl_xor(psum, 2);
        psum += __shfl_xor(psum, 4);
        l_run = l_run * scale + psum;
        m_run = m_new;
        #pragma unroll
        for (int i = 0; i < 8; ++i) o[i] *= scale;
        __syncthreads();
        #pragma unroll 4
        for (int j = 0; j < 32; ++j) {
            float p = Ps[row][j];
            #pragma unroll
            for (int i = 0; i < 8; ++i)
                o[i] = fmaf(p, vs[j][col * 8 + i], o[i]);
        }
    }
    float inv = 1.f / l_run;
    float* dst = &O[base + (size_t)(q0 + row) * D_ + col * 8];
    #pragma unroll
    for (int i = 0; i < 8; ++i) dst[i] = o[i] * inv;
}

// ---------------------------------------------------------------------------
// y = x + gamma*(a - mean)/sqrt(var_unbiased + eps) + beta ; one block per row
// ---------------------------------------------------------------------------
__global__ __launch_bounds__(256) void add_ln_kernel(
    const float* __restrict__ x, const float* __restrict__ a,
    const float* __restrict__ g, const float* __restrict__ beta,
    float* __restrict__ y)
{
    int rowid = blockIdx.x;
    int tid = threadIdx.x;
    const float2 a2 = reinterpret_cast<const float2*>(a + (size_t)rowid * D_)[tid];
    float s = a2.x + a2.y;
    float ss = a2.x * a2.x + a2.y * a2.y;
    #pragma unroll
    for (int off = 32; off > 0; off >>= 1) {
        s += __shfl_down(s, off);
        ss += __shfl_down(ss, off);
    }
    __shared__ float ws_s[4], ws_ss[4];
    __shared__ float s_mean, s_rstd;
    int wave = tid >> 6, lane = tid & 63;
    if (lane == 0) { ws_s[wave] = s; ws_ss[wave] = ss; }
    __syncthreads();
    if (tid == 0) {
        float st = ws_s[0] + ws_s[1] + ws_s[2] + ws_s[3];
        float sst = ws_ss[0] + ws_ss[1] + ws_ss[2] + ws_ss[3];
        float mean = st / (float)D_;
        float var = (sst - (float)D_ * mean * mean) / (float)(D_ - 1);
        s_mean = mean;
        s_rstd = rsqrtf(var + EPS_);
    }
    __syncthreads();
    float mean = s_mean, rstd = s_rstd, gg = g[0], bb = beta[0];
    const float2 x2 = reinterpret_cast<const float2*>(x + (size_t)rowid * D_)[tid];
    float2 o;
    o.x = x2.x + gg * (a2.x - mean) * rstd + bb;
    o.y = x2.y + gg * (a2.y - mean) * rstd + bb;
    reinterpret_cast<float2*>(y + (size_t)rowid * D_)[tid] = o;
}

// ---------------------------------------------------------------------------
extern "C" void kernel_launch(void* const* d_in, const int* in_sizes, int n_in,
                              void* d_out, int out_size, void* d_ws, size_t ws_size,
                              hipStream_t stream) {
    const float* x  = (const float*)d_in[0];
    const unsigned char* mask = (const unsigned char*)d_in[1];
    const float* wq = (const float*)d_in[2];
    const float* bq = (const float*)d_in[3];
    const float* wk = (const float*)d_in[4];
    const float* bk = (const float*)d_in[5];
    const float* wv = (const float*)d_in[6];
    const float* bv = (const float*)d_in[7];
    const float* wo = (const float*)d_in[8];
    const float* bo = (const float*)d_in[9];
    const float* w1 = (const float*)d_in[10];
    const float* b1 = (const float*)d_in[11];
    const float* w2 = (const float*)d_in[12];
    const float* b2 = (const float*)d_in[13];
    const float* g1 = (const float*)d_in[14];
    const float* be1 = (const float*)d_in[15];
    const float* g2 = (const float*)d_in[16];
    const float* be2 = (const float*)d_in[17];
    float* out = (float*)d_out;
    float* ws = (float*)d_ws;

    const size_t MS = (size_t)B_ * S_;  // 8192 rows
    float* Q   = ws;
    float* Km  = ws + 1 * MS * D_;
    float* V   = ws + 2 * MS * D_;
    float* O   = ws + 3 * MS * D_;
    float* att = ws + 4 * MS * D_;
    float* y   = ws + 5 * MS * D_;
    float* ff1 = ws;                 // reuse Q..O region (MS*DFF = 4*MS*D floats)
    float* ff2 = att;                // reuse att
    int*   cm  = (int*)(ws + 6 * MS * D_);

    dim3 blk(256);
    mask_canon_kernel<<<1, blk, 0, stream>>>(mask, cm);

    dim3 gD(D_ / 64, MS / 64);
    gemm_bias_kernel<<<gD, blk, 0, stream>>>(x, wq, bq, Q, MS, D_, D_, 0);
    gemm_bias_kernel<<<gD, blk, 0, stream>>>(x, wk, bk, Km, MS, D_, D_, 0);
    gemm_bias_kernel<<<gD, blk, 0, stream>>>(x, wv, bv, V, MS, D_, D_, 0);

    attn_kernel<<<dim3(S_ / 32, H_, B_), blk, 0, stream>>>(Q, Km, V, cm, O);

    gemm_bias_kernel<<<gD, blk, 0, stream>>>(O, wo, bo, att, MS, D_, D_, 0);
    add_ln_kernel<<<dim3((unsigned)MS), blk, 0, stream>>>(x, att, g1, be1, y);

    gemm_bias_kernel<<<dim3(DFF_ / 64, MS / 64), blk, 0, stream>>>(y, w1, b1, ff1, MS, DFF_, D_, 1);
    gemm_bias_kernel<<<gD, blk, 0, stream>>>(ff1, w2, b2, ff2, MS, D_, DFF_, 0);
    add_ln_kernel<<<dim3((unsigned)MS), blk, 0, stream>>>(y, ff2, g2, be2, out);
}

// Round 2
// 399.620 us; speedup vs baseline: 6.7129x; 6.7129x over previous
//
#include <hip/hip_runtime.h>
#include <hip/hip_bf16.h>
#include <math.h>

#define B_ 4
#define S_ 2048
#define D_ 512
#define H_ 8
#define DK_ 64
#define DFF_ 2048
#define NEG_ (-1.0e9f)
#define EPS_ 1e-6f

typedef __attribute__((ext_vector_type(8))) short bf16x8;
typedef __attribute__((ext_vector_type(4))) float f32x4;
typedef unsigned short ushort_t;

__device__ inline unsigned short f2bf(float f) {
    unsigned u = __float_as_uint(f);
    unsigned r = u + 0x7FFFu + ((u >> 16) & 1u);
    return (unsigned short)(r >> 16);
}

__device__ inline f32x4 mfma16(bf16x8 a, bf16x8 b, f32x4 c) {
    return __builtin_amdgcn_mfma_f32_16x16x32_bf16(a, b, c, 0, 0, 0);
}

// global -> LDS direct, 16B per lane. LDS dest is wave-uniform base + lane*16.
__device__ inline void gload16(const void* g, void* l) {
    __builtin_amdgcn_global_load_lds(
        (const __attribute__((address_space(1))) unsigned int*)g,
        (__attribute__((address_space(3))) unsigned int*)l, 16, 0, 0);
}

// ---------------------------------------------------------------------------
// Mask canonicalization (unchanged from passing baseline).
// ---------------------------------------------------------------------------
__global__ void mask_canon_kernel(const unsigned char* __restrict__ mraw,
                                  int* __restrict__ cm) {
    __shared__ int s_bad;
    int tid = threadIdx.x;
    if (tid == 0) s_bad = 0;
    __syncthreads();
    const unsigned int* w = (const unsigned int*)mraw;
    int bad = 0;
    for (int i = tid; i < (B_ * S_) / 4; i += 256) {
        unsigned int v = w[i];
        if (!(v == 0u || v == 1u || v == 0x3F800000u)) bad = 1;
    }
    if (bad) atomicOr(&s_bad, 1);
    __syncthreads();
    if (s_bad) {
        for (int i = tid; i < B_ * S_; i += 256) cm[i] = mraw[i] ? 1 : 0;
    } else {
        for (int i = tid; i < B_ * S_; i += 256) cm[i] = w[i] ? 1 : 0;
    }
}

// ---------------------------------------------------------------------------
// f32 -> bf16 convert (vectorized), n4 = n/4
// ---------------------------------------------------------------------------
__global__ __launch_bounds__(256) void f32_to_bf16_kernel(
    const float* __restrict__ src, unsigned short* __restrict__ dst, int n4) {
    int i = blockIdx.x * 256 + threadIdx.x;
    if (i < n4) {
        float4 v = reinterpret_cast<const float4*>(src)[i];
        ushort4 o;
        o.x = f2bf(v.x); o.y = f2bf(v.y); o.z = f2bf(v.z); o.w = f2bf(v.w);
        reinterpret_cast<ushort4*>(dst)[i] = o;
    }
}

// ---------------------------------------------------------------------------
// MFMA GEMM: C[M,N] = A[M,K](bf16) @ W[N,K](bf16)^T + bias(f32)
// BK=64, 256 threads = 4 waves in 2x2 grid; per-wave FMx FN fragments of 16x16.
// LDS tiles row-major [rows][64 bf16] with XOR slot swizzle (slot ^= row&7),
// staged via global_load_lds with pre-swizzled per-lane SOURCE address.
// ---------------------------------------------------------------------------
template<int BM, int BN, bool RELU, bool OUT_BF16>
__global__ __launch_bounds__(256) void gemm_mfma(
    const unsigned short* __restrict__ A, const unsigned short* __restrict__ W,
    const float* __restrict__ bias, void* __restrict__ Cout,
    int M, int N, int K)
{
    constexpr int FM = BM / 32;   // frags per wave (M), wave grid 2x2
    constexpr int FN = BN / 32;
    __shared__ unsigned short Asl[BM * 64];
    __shared__ unsigned short Bsl[BN * 64];

    const int tid = threadIdx.x;
    const int w = tid >> 6, lane = tid & 63;
    const int lr = lane & 15, lg = lane >> 4;
    const int wm = w >> 1, wn = w & 1;
    const int m0 = blockIdx.y * BM, n0 = blockIdx.x * BN;
    const int srow = lane >> 3;    // 0..7 row within an 8-row staging instr
    const int schunk = lane & 7;   // 16B chunk slot within 128B row

    f32x4 acc[FM][FN] = {};

    for (int k0 = 0; k0 < K; k0 += 64) {
        __syncthreads();
        #pragma unroll
        for (int j = 0; j < BM / 32; ++j) {
            int instr = w * (BM / 32) + j;
            int row = instr * 8 + srow;
            const unsigned short* src =
                A + (size_t)(m0 + row) * K + k0 + ((schunk ^ (row & 7)) * 8);
            gload16(src, &Asl[instr * 512]);
        }
        #pragma unroll
        for (int j = 0; j < BN / 32; ++j) {
            int instr = w * (BN / 32) + j;
            int row = instr * 8 + srow;
            const unsigned short* src =
                W + (size_t)(n0 + row) * K + k0 + ((schunk ^ (row & 7)) * 8);
            gload16(src, &Bsl[instr * 512]);
        }
        __syncthreads();

        bf16x8 af[FM][2], bfr[FN][2];
        #pragma unroll
        for (int m = 0; m < FM; ++m)
            #pragma unroll
            for (int ko = 0; ko < 2; ++ko) {
                int row = wm * (FM * 16) + m * 16 + lr;
                int slot = (lg + 4 * ko) ^ (row & 7);
                af[m][ko] = *(const bf16x8*)&Asl[row * 64 + slot * 8];
            }
        #pragma unroll
        for (int n = 0; n < FN; ++n)
            #pragma unroll
            for (int ko = 0; ko < 2; ++ko) {
                int row = wn * (FN * 16) + n * 16 + lr;
                int slot = (lg + 4 * ko) ^ (row & 7);
                bfr[n][ko] = *(const bf16x8*)&Bsl[row * 64 + slot * 8];
            }
        #pragma unroll
        for (int m = 0; m < FM; ++m)
            #pragma unroll
            for (int n = 0; n < FN; ++n)
                #pragma unroll
                for (int ko = 0; ko < 2; ++ko)
                    acc[m][n] = mfma16(af[m][ko], bfr[n][ko], acc[m][n]);
    }

    // epilogue: C/D frag layout col=lane&15, row=(lane>>4)*4+r
    #pragma unroll
    for (int n = 0; n < FN; ++n) {
        int col = n0 + wn * (FN * 16) + n * 16 + lr;
        float bv = bias[col];
        #pragma unroll
        for (int m = 0; m < FM; ++m) {
            int rowb = m0 + wm * (FM * 16) + m * 16 + lg * 4;
            #pragma unroll
            for (int r = 0; r < 4; ++r) {
                float v = acc[m][n][r] + bv;
                if (RELU) v = fmaxf(v, 0.f);
                if (OUT_BF16)
                    ((unsigned short*)Cout)[(size_t)(rowb + r) * N + col] = f2bf(v);
                else
                    ((float*)Cout)[(size_t)(rowb + r) * N + col] = v;
            }
        }
    }
}

// ---------------------------------------------------------------------------
// MFMA flash attention. QKV packed [B*S][1536] bf16 (Q|K|V each 512 cols,
// head h at col h*64). Block = 256 thr = 4 waves; wave handles 16 q-rows,
// block handles 64 q-rows of one (b,h). KV tiles of 64, online softmax.
// K LDS: [64 rows][64 bf16] XOR-swizzled.  V LDS: transposed [d][kv] swizzled.
// P round-trips through per-wave swizzled LDS to reach MFMA A-layout.
// ---------------------------------------------------------------------------
__global__ __launch_bounds__(256) void attn_mfma(
    const unsigned short* __restrict__ QKV, const int* __restrict__ cmask,
    unsigned short* __restrict__ O)
{
    __shared__ unsigned short Ks[64 * 64];
    __shared__ unsigned short VTs[64 * 64];
    __shared__ unsigned short Ps[4 * 16 * 64];

    const int tid = threadIdx.x;
    const int w = tid >> 6, lane = tid & 63;
    const int lr = lane & 15, lg = lane >> 4;
    const int q0 = blockIdx.x * 64;
    const int h = blockIdx.y, b = blockIdx.z;
    const int srow = lane >> 3, schunk = lane & 7;
    const size_t RS = 1536;

    // Q fragments (A-layout: lane holds Q[lr][8*lg + i + 32*ko]), held in regs
    bf16x8 qf[2];
    {
        const unsigned short* qp =
            QKV + (size_t)(b * S_ + q0 + w * 16 + lr) * RS + h * 64 + lg * 8;
        qf[0] = *(const bf16x8*)(qp);
        qf[1] = *(const bf16x8*)(qp + 32);
    }

    f32x4 od[4] = {};
    float m_run[4] = {-INFINITY, -INFINITY, -INFINITY, -INFINITY};
    float ps[4] = {0.f, 0.f, 0.f, 0.f};

    for (int kv0 = 0; kv0 < S_; kv0 += 64) {
        __syncthreads();
        // stage K (swizzled b128 write) and V (transposed scatter, swizzled)
        #pragma unroll
        for (int j = 0; j < 2; ++j) {
            int row = w * 16 + j * 8 + srow;
            const unsigned short* kp =
                QKV + (size_t)(b * S_ + kv0 + row) * RS + 512 + h * 64 + schunk * 8;
            bf16x8 k8 = *(const bf16x8*)kp;
            *(bf16x8*)&Ks[row * 64 + ((schunk ^ (row & 7)) * 8)] = k8;
            const unsigned short* vp =
                QKV + (size_t)(b * S_ + kv0 + row) * RS + 1024 + h * 64 + schunk * 8;
            bf16x8 v8 = *(const bf16x8*)vp;
            #pragma unroll
            for (int i = 0; i < 8; ++i) {
                int d = schunk * 8 + i;                  // d&7 == i
                VTs[((d * 64 + row) ^ (i << 3))] = (unsigned short)v8[i];
            }
        }
        int mk[4];
        #pragma unroll
        for (int n = 0; n < 4; ++n) mk[n] = cmask[b * S_ + kv0 + n * 16 + lr];
        __syncthreads();

        // QK^T: S[16 q][64 kv], 4 col-chunks of 16
        float sc[4][4];
        #pragma unroll
        for (int n = 0; n < 4; ++n) {
            f32x4 s = {};
            #pragma unroll
            for (int ko = 0; ko < 2; ++ko) {
                int row = n * 16 + lr;
                int slot = (lg + 4 * ko) ^ (row & 7);
                bf16x8 kf = *(const bf16x8*)&Ks[row * 64 + slot * 8];
                s = mfma16(qf[ko], kf, s);
            }
            #pragma unroll
            for (int r = 0; r < 4; ++r)
                sc[n][r] = mk[n] ? NEG_ : s[r] * 0.125f;
        }

        // online softmax (rows live across 16 lanes sharing lg)
        float mt[4], mnew[4], scl[4];
        #pragma unroll
        for (int r = 0; r < 4; ++r) {
            mt[r] = fmaxf(fmaxf(sc[0][r], sc[1][r]), fmaxf(sc[2][r], sc[3][r]));
            mt[r] = fmaxf(mt[r], __shfl_xor(mt[r], 1));
            mt[r] = fmaxf(mt[r], __shfl_xor(mt[r], 2));
            mt[r] = fmaxf(mt[r], __shfl_xor(mt[r], 4));
            mt[r] = fmaxf(mt[r], __shfl_xor(mt[r], 8));
            mnew[r] = fmaxf(m_run[r], mt[r]);
            scl[r] = __expf(m_run[r] - mnew[r]);
            m_run[r] = mnew[r];
        }
        float psum[4] = {0.f, 0.f, 0.f, 0.f};
        #pragma unroll
        for (int n = 0; n < 4; ++n) {
            #pragma unroll
            for (int r = 0; r < 4; ++r) {
                float p = __expf(sc[n][r] - mnew[r]);
                psum[r] += p;
                int prow = lg * 4 + r, pcol = n * 16 + lr;
                Ps[w * 1024 + ((prow * 64 + pcol) ^ ((prow & 7) << 3))] = f2bf(p);
            }
        }
        #pragma unroll
        for (int r = 0; r < 4; ++r) {
            ps[r] = ps[r] * scl[r] + psum[r];
            #pragma unroll
            for (int nd = 0; nd < 4; ++nd) od[nd][r] *= scl[r];
        }

        // P A-frags (same-wave LDS round trip; DS ops in-order per wave)
        bf16x8 pa[2];
        #pragma unroll
        for (int ko = 0; ko < 2; ++ko) {
            int slot = (lg + 4 * ko) ^ (lr & 7);
            pa[ko] = *(const bf16x8*)&Ps[w * 1024 + lr * 64 + slot * 8];
        }
        // PV: O[16 q][64 d] accumulate
        #pragma unroll
        for (int nd = 0; nd < 4; ++nd) {
            #pragma unroll
            for (int ko = 0; ko < 2; ++ko) {
                int rowv = nd * 16 + lr;
                int slot = (lg + 4 * ko) ^ (rowv & 7);
                bf16x8 vf = *(const bf16x8*)&VTs[rowv * 64 + slot * 8];
                od[nd] = mfma16(pa[ko], vf, od[nd]);
            }
        }
    }

    // finalize: full row-sums, normalize, write O (bf16, [B*S][512])
    float inv[4];
    #pragma unroll
    for (int r = 0; r < 4; ++r) {
        float t = ps[r];
        t += __shfl_xor(t, 1);
        t += __shfl_xor(t, 2);
        t += __shfl_xor(t, 4);
        t += __shfl_xor(t, 8);
        inv[r] = 1.f / t;
    }
    #pragma unroll
    for (int nd = 0; nd < 4; ++nd)
        #pragma unroll
        for (int r = 0; r < 4; ++r) {
            size_t row = (size_t)(b * S_ + q0 + w * 16 + lg * 4 + r);
            O[row * 512 + h * 64 + nd * 16 + lr] = f2bf(od[nd][r] * inv[r]);
        }
}

// ---------------------------------------------------------------------------
// y = x + gamma*(a-mean)/sqrt(var_ddof1+eps) + beta ; optional bf16 copy of y
// ---------------------------------------------------------------------------
__global__ __launch_bounds__(256) void add_ln_kernel(
    const float* __restrict__ x, const float* __restrict__ a,
    const float* __restrict__ g, const float* __restrict__ beta,
    float* __restrict__ y, unsigned short* __restrict__ ybf)
{
    int rowid = blockIdx.x;
    int tid = threadIdx.x;
    const float2 a2 = reinterpret_cast<const float2*>(a + (size_t)rowid * D_)[tid];
    float s = a2.x + a2.y;
    float ss = a2.x * a2.x + a2.y * a2.y;
    #pragma unroll
    for (int off = 32; off > 0; off >>= 1) {
        s += __shfl_down(s, off);
        ss += __shfl_down(ss, off);
    }
    __shared__ float ws_s[4], ws_ss[4];
    __shared__ float s_mean, s_rstd;
    int wave = tid >> 6, lane = tid & 63;
    if (lane == 0) { ws_s[wave] = s; ws_ss[wave] = ss; }
    __syncthreads();
    if (tid == 0) {
        float st = ws_s[0] + ws_s[1] + ws_s[2] + ws_s[3];
        float sst = ws_ss[0] + ws_ss[1] + ws_ss[2] + ws_ss[3];
        float mean = st / (float)D_;
        float var = (sst - (float)D_ * mean * mean) / (float)(D_ - 1);
        s_mean = mean;
        s_rstd = rsqrtf(var + EPS_);
    }
    __syncthreads();
    float mean = s_mean, rstd = s_rstd, gg = g[0], bb = beta[0];
    const float2 x2 = reinterpret_cast<const float2*>(x + (size_t)rowid * D_)[tid];
    float2 o;
    o.x = x2.x + gg * (a2.x - mean) * rstd + bb;
    o.y = x2.y + gg * (a2.y - mean) * rstd + bb;
    reinterpret_cast<float2*>(y + (size_t)rowid * D_)[tid] = o;
    if (ybf) {
        ushort2 ob; ob.x = f2bf(o.x); ob.y = f2bf(o.y);
        reinterpret_cast<ushort2*>(ybf + (size_t)rowid * D_)[tid] = ob;
    }
}

// ---------------------------------------------------------------------------
extern "C" void kernel_launch(void* const* d_in, const int* in_sizes, int n_in,
                              void* d_out, int out_size, void* d_ws, size_t ws_size,
                              hipStream_t stream) {
    const float* x  = (const float*)d_in[0];
    const unsigned char* mask = (const unsigned char*)d_in[1];
    const float* wq = (const float*)d_in[2];
    const float* bq = (const float*)d_in[3];
    const float* wk = (const float*)d_in[4];
    const float* bk = (const float*)d_in[5];
    const float* wv = (const float*)d_in[6];
    const float* bv = (const float*)d_in[7];
    const float* wo = (const float*)d_in[8];
    const float* bo = (const float*)d_in[9];
    const float* w1 = (const float*)d_in[10];
    const float* b1 = (const float*)d_in[11];
    const float* w2 = (const float*)d_in[12];
    const float* b2 = (const float*)d_in[13];
    const float* g1 = (const float*)d_in[14];
    const float* be1 = (const float*)d_in[15];
    const float* g2 = (const float*)d_in[16];
    const float* be2 = (const float*)d_in[17];
    float* out = (float*)d_out;
    char* base = (char*)d_ws;

    const size_t MS = (size_t)B_ * S_;                       // 8192
    unsigned short* QKV  = (unsigned short*)(base);                 // 24 MB
    unsigned short* Ob   = (unsigned short*)(base + 25165824);      // 8 MB
    unsigned short* ff1  = QKV;                                     // 32 MB overlay (QKV+Ob dead)
    float*          att  = (float*)(base + 33554432);               // 16 MB
    float*          ff2  = att;                                     // overlay (att dead)
    float*          y    = (float*)(base + 50331648);               // 16 MB
    unsigned short* ybf  = (unsigned short*)(base + 67108864);      // 8 MB
    unsigned short* xb   = (unsigned short*)(base + 75497472);      // 8 MB
    unsigned short* wqkvb= (unsigned short*)(base + 83886080);      // 1.5 MB
    unsigned short* wob  = (unsigned short*)(base + 85458944);      // 0.5 MB
    unsigned short* w1b  = (unsigned short*)(base + 85983232);      // 2 MB
    unsigned short* w2b  = (unsigned short*)(base + 88080384);      // 2 MB
    float*          bqkv = (float*)(base + 90177536);               // 6 KB
    int*            cm   = (int*)(base + 90183680);                 // 32 KB

    dim3 blk(256);
    mask_canon_kernel<<<1, blk, 0, stream>>>(mask, cm);

    // bf16 conversions
    f32_to_bf16_kernel<<<(B_*S_*D_/4 + 255)/256, blk, 0, stream>>>(x, xb, B_*S_*D_/4);
    f32_to_bf16_kernel<<<(D_*D_/4 + 255)/256, blk, 0, stream>>>(wq, wqkvb,            D_*D_/4);
    f32_to_bf16_kernel<<<(D_*D_/4 + 255)/256, blk, 0, stream>>>(wk, wqkvb + D_*D_,    D_*D_/4);
    f32_to_bf16_kernel<<<(D_*D_/4 + 255)/256, blk, 0, stream>>>(wv, wqkvb + 2*D_*D_,  D_*D_/4);
    f32_to_bf16_kernel<<<(D_*D_/4 + 255)/256, blk, 0, stream>>>(wo, wob, D_*D_/4);
    f32_to_bf16_kernel<<<(DFF_*D_/4 + 255)/256, blk, 0, stream>>>(w1, w1b, DFF_*D_/4);
    f32_to_bf16_kernel<<<(DFF_*D_/4 + 255)/256, blk, 0, stream>>>(w2, w2b, DFF_*D_/4);

    // concat biases bq|bk|bv
    hipMemcpyAsync(bqkv,        bq, D_ * sizeof(float), hipMemcpyDeviceToDevice, stream);
    hipMemcpyAsync(bqkv + D_,   bk, D_ * sizeof(float), hipMemcpyDeviceToDevice, stream);
    hipMemcpyAsync(bqkv + 2*D_, bv, D_ * sizeof(float), hipMemcpyDeviceToDevice, stream);

    // fused QKV projection: [8192,1536] = xb @ [1536,512]^T
    gemm_mfma<128,128,false,true><<<dim3(1536/128, MS/128), blk, 0, stream>>>(
        xb, wqkvb, bqkv, QKV, MS, 1536, D_);

    attn_mfma<<<dim3(S_/64, H_, B_), blk, 0, stream>>>(QKV, cm, Ob);

    // out-proj -> att (f32)
    gemm_mfma<128,64,false,false><<<dim3(D_/64, MS/128), blk, 0, stream>>>(
        Ob, wob, bo, att, MS, D_, D_);

    add_ln_kernel<<<dim3((unsigned)MS), blk, 0, stream>>>(x, att, g1, be1, y, ybf);

    // FFN
    gemm_mfma<128,128,true,true><<<dim3(DFF_/128, MS/128), blk, 0, stream>>>(
        ybf, w1b, b1, ff1, MS, DFF_, D_);
    gemm_mfma<128,64,false,false><<<dim3(D_/64, MS/128), blk, 0, stream>>>(
        ff1, w2b, b2, ff2, MS, D_, DFF_);

    add_ln_kernel<<<dim3((unsigned)MS), blk, 0, stream>>>(y, ff2, g2, be2, out, nullptr);
}

// Round 3
// 333.089 us; speedup vs baseline: 8.0537x; 1.1997x over previous
//
#include <hip/hip_runtime.h>
#include <hip/hip_bf16.h>
#include <math.h>

#define B_ 4
#define S_ 2048
#define D_ 512
#define H_ 8
#define DK_ 64
#define DFF_ 2048
#define NEG_ (-1.0e9f)
#define EPS_ 1e-6f

typedef __attribute__((ext_vector_type(8))) short bf16x8;
typedef __attribute__((ext_vector_type(4))) float f32x4;

__device__ inline unsigned short f2bf(float f) {
    unsigned u = __float_as_uint(f);
    unsigned r = u + 0x7FFFu + ((u >> 16) & 1u);
    return (unsigned short)(r >> 16);
}

__device__ inline f32x4 mfma16(bf16x8 a, bf16x8 b, f32x4 c) {
    return __builtin_amdgcn_mfma_f32_16x16x32_bf16(a, b, c, 0, 0, 0);
}

// global -> LDS direct. LDS dest = wave-uniform base + lane*size.
__device__ inline void gload16(const void* g, void* l) {
    __builtin_amdgcn_global_load_lds(
        (const __attribute__((address_space(1))) unsigned int*)g,
        (__attribute__((address_space(3))) unsigned int*)l, 16, 0, 0);
}
__device__ inline void gload4(const void* g, void* l) {
    __builtin_amdgcn_global_load_lds(
        (const __attribute__((address_space(1))) unsigned int*)g,
        (__attribute__((address_space(3))) unsigned int*)l, 4, 0, 0);
}

// ---------------------------------------------------------------------------
// Mask canonicalization -> additive f32 bias (0 or NEG). Handles u8 / 4-byte.
// ---------------------------------------------------------------------------
__global__ void mask_canon_kernel(const unsigned char* __restrict__ mraw,
                                  float* __restrict__ mb) {
    __shared__ int s_bad;
    int tid = threadIdx.x;
    if (tid == 0) s_bad = 0;
    __syncthreads();
    const unsigned int* w = (const unsigned int*)mraw;
    int bad = 0;
    for (int i = tid; i < (B_ * S_) / 4; i += 256) {
        unsigned int v = w[i];
        if (!(v == 0u || v == 1u || v == 0x3F800000u)) bad = 1;
    }
    if (bad) atomicOr(&s_bad, 1);
    __syncthreads();
    if (s_bad) {  // u8 layout
        for (int i = tid; i < B_ * S_; i += 256) mb[i] = mraw[i] ? NEG_ : 0.f;
    } else {      // 4-byte layout
        for (int i = tid; i < B_ * S_; i += 256) mb[i] = w[i] ? NEG_ : 0.f;
    }
}

// ---------------------------------------------------------------------------
// f32 -> bf16 convert (vectorized), n4 = n/4
// ---------------------------------------------------------------------------
__global__ __launch_bounds__(256) void f32_to_bf16_kernel(
    const float* __restrict__ src, unsigned short* __restrict__ dst, int n4) {
    int i = blockIdx.x * 256 + threadIdx.x;
    if (i < n4) {
        float4 v = reinterpret_cast<const float4*>(src)[i];
        ushort4 o;
        o.x = f2bf(v.x); o.y = f2bf(v.y); o.z = f2bf(v.z); o.w = f2bf(v.w);
        reinterpret_cast<ushort4*>(dst)[i] = o;
    }
}

// ---------------------------------------------------------------------------
// Generic MFMA GEMM: C[M,N] = A[M,K](bf16) @ W[N,K](bf16)^T + bias(f32)
// ---------------------------------------------------------------------------
template<int BM, int BN, bool RELU, bool OUT_BF16>
__global__ __launch_bounds__(256) void gemm_mfma(
    const unsigned short* __restrict__ A, const unsigned short* __restrict__ W,
    const float* __restrict__ bias, void* __restrict__ Cout,
    int M, int N, int K)
{
    constexpr int FM = BM / 32;
    constexpr int FN = BN / 32;
    __shared__ unsigned short Asl[BM * 64];
    __shared__ unsigned short Bsl[BN * 64];

    const int tid = threadIdx.x;
    const int w = tid >> 6, lane = tid & 63;
    const int lr = lane & 15, lg = lane >> 4;
    const int wm = w >> 1, wn = w & 1;
    const int m0 = blockIdx.y * BM, n0 = blockIdx.x * BN;
    const int srow = lane >> 3;
    const int schunk = lane & 7;

    f32x4 acc[FM][FN] = {};

    for (int k0 = 0; k0 < K; k0 += 64) {
        __syncthreads();
        #pragma unroll
        for (int j = 0; j < BM / 32; ++j) {
            int instr = w * (BM / 32) + j;
            int row = instr * 8 + srow;
            const unsigned short* src =
                A + (size_t)(m0 + row) * K + k0 + ((schunk ^ (row & 7)) * 8);
            gload16(src, &Asl[instr * 512]);
        }
        #pragma unroll
        for (int j = 0; j < BN / 32; ++j) {
            int instr = w * (BN / 32) + j;
            int row = instr * 8 + srow;
            const unsigned short* src =
                W + (size_t)(n0 + row) * K + k0 + ((schunk ^ (row & 7)) * 8);
            gload16(src, &Bsl[instr * 512]);
        }
        __syncthreads();

        bf16x8 af[FM][2], bfr[FN][2];
        #pragma unroll
        for (int m = 0; m < FM; ++m)
            #pragma unroll
            for (int ko = 0; ko < 2; ++ko) {
                int row = wm * (FM * 16) + m * 16 + lr;
                int slot = (lg + 4 * ko) ^ (row & 7);
                af[m][ko] = *(const bf16x8*)&Asl[row * 64 + slot * 8];
            }
        #pragma unroll
        for (int n = 0; n < FN; ++n)
            #pragma unroll
            for (int ko = 0; ko < 2; ++ko) {
                int row = wn * (FN * 16) + n * 16 + lr;
                int slot = (lg + 4 * ko) ^ (row & 7);
                bfr[n][ko] = *(const bf16x8*)&Bsl[row * 64 + slot * 8];
            }
        #pragma unroll
        for (int m = 0; m < FM; ++m)
            #pragma unroll
            for (int n = 0; n < FN; ++n)
                #pragma unroll
                for (int ko = 0; ko < 2; ++ko)
                    acc[m][n] = mfma16(af[m][ko], bfr[n][ko], acc[m][n]);
    }

    #pragma unroll
    for (int n = 0; n < FN; ++n) {
        int col = n0 + wn * (FN * 16) + n * 16 + lr;
        float bv = bias[col];
        #pragma unroll
        for (int m = 0; m < FM; ++m) {
            int rowb = m0 + wm * (FM * 16) + m * 16 + lg * 4;
            #pragma unroll
            for (int r = 0; r < 4; ++r) {
                float v = acc[m][n][r] + bv;
                if (RELU) v = fmaxf(v, 0.f);
                if (OUT_BF16)
                    ((unsigned short*)Cout)[(size_t)(rowb + r) * N + col] = f2bf(v);
                else
                    ((float*)Cout)[(size_t)(rowb + r) * N + col] = v;
            }
        }
    }
}

// ---------------------------------------------------------------------------
// QKV GEMM: A[8192,512] @ Wqkv[1536,512]^T + bias.
// Cols [0,1024) -> QKb [8192][1024] (Q|K packed).
// Cols [1024,1536) -> VT [b][h][d=64][s=2048] bf16, packed ushort4 along s.
// ---------------------------------------------------------------------------
__global__ __launch_bounds__(256) void gemm_qkv(
    const unsigned short* __restrict__ A, const unsigned short* __restrict__ W,
    const float* __restrict__ bias, unsigned short* __restrict__ QKb,
    unsigned short* __restrict__ VTg)
{
    constexpr int K = 512;
    __shared__ unsigned short Asl[128 * 64];
    __shared__ unsigned short Bsl[128 * 64];

    const int tid = threadIdx.x;
    const int w = tid >> 6, lane = tid & 63;
    const int lr = lane & 15, lg = lane >> 4;
    const int wm = w >> 1, wn = w & 1;
    const int m0 = blockIdx.y * 128, n0 = blockIdx.x * 128;
    const int srow = lane >> 3;
    const int schunk = lane & 7;

    f32x4 acc[4][4] = {};

    for (int k0 = 0; k0 < K; k0 += 64) {
        __syncthreads();
        #pragma unroll
        for (int j = 0; j < 4; ++j) {
            int instr = w * 4 + j;
            int row = instr * 8 + srow;
            gload16(A + (size_t)(m0 + row) * K + k0 + ((schunk ^ (row & 7)) * 8),
                    &Asl[instr * 512]);
            gload16(W + (size_t)(n0 + row) * K + k0 + ((schunk ^ (row & 7)) * 8),
                    &Bsl[instr * 512]);
        }
        __syncthreads();

        bf16x8 af[4][2], bfr[4][2];
        #pragma unroll
        for (int m = 0; m < 4; ++m)
            #pragma unroll
            for (int ko = 0; ko < 2; ++ko) {
                int row = wm * 64 + m * 16 + lr;
                int slot = (lg + 4 * ko) ^ (row & 7);
                af[m][ko] = *(const bf16x8*)&Asl[row * 64 + slot * 8];
            }
        #pragma unroll
        for (int n = 0; n < 4; ++n)
            #pragma unroll
            for (int ko = 0; ko < 2; ++ko) {
                int row = wn * 64 + n * 16 + lr;
                int slot = (lg + 4 * ko) ^ (row & 7);
                bfr[n][ko] = *(const bf16x8*)&Bsl[row * 64 + slot * 8];
            }
        #pragma unroll
        for (int m = 0; m < 4; ++m)
            #pragma unroll
            for (int n = 0; n < 4; ++n)
                #pragma unroll
                for (int ko = 0; ko < 2; ++ko)
                    acc[m][n] = mfma16(af[m][ko], bfr[n][ko], acc[m][n]);
    }

    if (n0 < 1024) {
        #pragma unroll
        for (int n = 0; n < 4; ++n) {
            int col = n0 + wn * 64 + n * 16 + lr;
            float bv = bias[col];
            #pragma unroll
            for (int m = 0; m < 4; ++m) {
                int rowb = m0 + wm * 64 + m * 16 + lg * 4;
                #pragma unroll
                for (int r = 0; r < 4; ++r)
                    QKb[(size_t)(rowb + r) * 1024 + col] = f2bf(acc[m][n][r] + bv);
            }
        }
    } else {
        #pragma unroll
        for (int n = 0; n < 4; ++n) {
            int col = n0 + wn * 64 + n * 16 + lr;
            int dfull = col - 1024;
            int hh = dfull >> 6, dd = dfull & 63;
            float bv = bias[col];
            #pragma unroll
            for (int m = 0; m < 4; ++m) {
                int rowb = m0 + wm * 64 + m * 16 + lg * 4;
                int bb = rowb >> 11;
                int s = rowb & 2047;
                ushort4 pk;
                pk.x = f2bf(acc[m][n][0] + bv);
                pk.y = f2bf(acc[m][n][1] + bv);
                pk.z = f2bf(acc[m][n][2] + bv);
                pk.w = f2bf(acc[m][n][3] + bv);
                *(ushort4*)&VTg[(((size_t)bb * 8 + hh) * 64 + dd) * 2048 + s] = pk;
            }
        }
    }
}

// ---------------------------------------------------------------------------
// MFMA flash attention v3: swapped QK^T, V pre-transposed globally.
// Block = 4 waves; wave owns 32 q-rows (2 x 16), block = 128 q-rows of (b,h).
// KV tiles of 64. K and V^T staged via global_load_lds (swizzled source).
// P stays per-wave: packed b64 writes to swizzled LDS, b128 A-frag reads.
// ---------------------------------------------------------------------------
__global__ __launch_bounds__(256, 2) void attn_mfma2(
    const unsigned short* __restrict__ QKb, const unsigned short* __restrict__ VTg,
    const float* __restrict__ mb, unsigned short* __restrict__ Ob)
{
    __shared__ unsigned short Ks[64 * 64];     // [kv][d]   swizzled 16B chunks
    __shared__ unsigned short VTs[64 * 64];    // [d][kv]   swizzled 16B chunks
    __shared__ unsigned short Ps[4 * 32 * 64]; // per-wave [q][kv] swizzled
    __shared__ float Ms[64];                   // additive mask bias for tile

    const int tid = threadIdx.x;
    const int w = tid >> 6, lane = tid & 63;
    const int lr = lane & 15, lg = lane >> 4;
    const int q0 = blockIdx.x * 128;
    const int h = blockIdx.y, b = blockIdx.z;
    const int srow = lane >> 3;
    const int sc_x = (lane & 7) ^ srow;      // pre-swizzled source chunk
    const int bh = b * H_ + h;
    unsigned short* PsW = &Ps[w * 2048];

    // Q fragments: qf[qb][ko] = Q[q = q0+w*32+qb*16+lr][d = lg*8+32*ko ..]
    bf16x8 qf[2][2];
    #pragma unroll
    for (int qb = 0; qb < 2; ++qb)
        #pragma unroll
        for (int ko = 0; ko < 2; ++ko)
            qf[qb][ko] = *(const bf16x8*)(QKb +
                (size_t)(b * S_ + q0 + w * 32 + qb * 16 + lr) * 1024 +
                h * 64 + ko * 32 + lg * 8);

    f32x4 od[2][4] = {};
    float m_run[2] = {-INFINITY, -INFINITY};
    float l_run[2] = {0.f, 0.f};

    for (int kv0 = 0; kv0 < S_; kv0 += 64) {
        __syncthreads();
        #pragma unroll
        for (int j = 0; j < 2; ++j) {
            int rl = w * 16 + j * 8 + srow;
            gload16(QKb + (size_t)(b * S_ + kv0 + rl) * 1024 + 512 + h * 64 + sc_x * 8,
                    &Ks[(w * 2 + j) * 512]);
            gload16(VTg + ((size_t)bh * 64 + rl) * 2048 + kv0 + sc_x * 8,
                    &VTs[(w * 2 + j) * 512]);
        }
        if (w == 0) gload4(mb + (size_t)b * S_ + kv0 + lane, Ms);
        __syncthreads();

        // swapped QK^T: st[n][qb] reg r = S^T[kv=16n+4lg+r][q=qb*16+lr]
        f32x4 st[4][2] = {};
        #pragma unroll
        for (int ko = 0; ko < 2; ++ko)
            #pragma unroll
            for (int n = 0; n < 4; ++n) {
                bf16x8 kf = *(const bf16x8*)
                    &Ks[(n * 16 + lr) * 64 + (((lg + 4 * ko) ^ (lr & 7)) * 8)];
                st[n][0] = mfma16(kf, qf[0][ko], st[n][0]);
                st[n][1] = mfma16(kf, qf[1][ko], st[n][1]);
            }

        f32x4 mbr[4];
        #pragma unroll
        for (int n = 0; n < 4; ++n)
            mbr[n] = *(const f32x4*)&Ms[n * 16 + lg * 4];

        #pragma unroll
        for (int qb = 0; qb < 2; ++qb) {
            float mt = -INFINITY;
            #pragma unroll
            for (int n = 0; n < 4; ++n)
                #pragma unroll
                for (int r = 0; r < 4; ++r) {
                    float v = st[n][qb][r] * 0.125f + mbr[n][r];
                    st[n][qb][r] = v;
                    mt = fmaxf(mt, v);
                }
            mt = fmaxf(mt, __shfl_xor(mt, 16));
            mt = fmaxf(mt, __shfl_xor(mt, 32));
            float mnew = fmaxf(m_run[qb], mt);
            float scl = __expf(m_run[qb] - mnew);
            m_run[qb] = mnew;
            float psum = 0.f;
            #pragma unroll
            for (int n = 0; n < 4; ++n) {
                float p0 = __expf(st[n][qb][0] - mnew);
                float p1 = __expf(st[n][qb][1] - mnew);
                float p2 = __expf(st[n][qb][2] - mnew);
                float p3 = __expf(st[n][qb][3] - mnew);
                psum += (p0 + p1) + (p2 + p3);
                ushort4 pk;
                pk.x = f2bf(p0); pk.y = f2bf(p1); pk.z = f2bf(p2); pk.w = f2bf(p3);
                int chunk = (2 * n + (lg >> 1)) ^ (lr & 7);
                *(ushort4*)&PsW[(qb * 16 + lr) * 64 + chunk * 8 + (lg & 1) * 4] = pk;
            }
            psum += __shfl_xor(psum, 16);
            psum += __shfl_xor(psum, 32);
            l_run[qb] = l_run[qb] * scl + psum;
            #pragma unroll
            for (int r = 0; r < 4; ++r) {
                float sr = __shfl(scl, lg * 4 + r);
                #pragma unroll
                for (int nd = 0; nd < 4; ++nd) od[qb][nd][r] *= sr;
            }
        }

        // PV: od[qb][nd] += P[q][kv] * V^T[d][kv]
        #pragma unroll
        for (int ko = 0; ko < 2; ++ko) {
            int slotx = ((lg + 4 * ko) ^ (lr & 7)) * 8;
            bf16x8 pa0 = *(const bf16x8*)&PsW[(0  + lr) * 64 + slotx];
            bf16x8 pa1 = *(const bf16x8*)&PsW[(16 + lr) * 64 + slotx];
            #pragma unroll
            for (int nd = 0; nd < 4; ++nd) {
                bf16x8 vf = *(const bf16x8*)&VTs[(nd * 16 + lr) * 64 + slotx];
                od[0][nd] = mfma16(pa0, vf, od[0][nd]);
                od[1][nd] = mfma16(pa1, vf, od[1][nd]);
            }
        }
    }

    #pragma unroll
    for (int qb = 0; qb < 2; ++qb) {
        float linv = 1.f / l_run[qb];
        #pragma unroll
        for (int r = 0; r < 4; ++r) {
            float iv = __shfl(linv, lg * 4 + r);
            size_t row = (size_t)(b * S_ + q0 + w * 32 + qb * 16 + lg * 4 + r);
            #pragma unroll
            for (int nd = 0; nd < 4; ++nd)
                Ob[row * 512 + h * 64 + nd * 16 + lr] = f2bf(od[qb][nd][r] * iv);
        }
    }
}

// ---------------------------------------------------------------------------
// y = x + gamma*(a-mean)/sqrt(var_ddof1+eps) + beta ; optional bf16 copy of y
// ---------------------------------------------------------------------------
__global__ __launch_bounds__(256) void add_ln_kernel(
    const float* __restrict__ x, const float* __restrict__ a,
    const float* __restrict__ g, const float* __restrict__ beta,
    float* __restrict__ y, unsigned short* __restrict__ ybf)
{
    int rowid = blockIdx.x;
    int tid = threadIdx.x;
    const float2 a2 = reinterpret_cast<const float2*>(a + (size_t)rowid * D_)[tid];
    float s = a2.x + a2.y;
    float ss = a2.x * a2.x + a2.y * a2.y;
    #pragma unroll
    for (int off = 32; off > 0; off >>= 1) {
        s += __shfl_down(s, off);
        ss += __shfl_down(ss, off);
    }
    __shared__ float ws_s[4], ws_ss[4];
    __shared__ float s_mean, s_rstd;
    int wave = tid >> 6, lane = tid & 63;
    if (lane == 0) { ws_s[wave] = s; ws_ss[wave] = ss; }
    __syncthreads();
    if (tid == 0) {
        float st = ws_s[0] + ws_s[1] + ws_s[2] + ws_s[3];
        float sst = ws_ss[0] + ws_ss[1] + ws_ss[2] + ws_ss[3];
        float mean = st / (float)D_;
        float var = (sst - (float)D_ * mean * mean) / (float)(D_ - 1);
        s_mean = mean;
        s_rstd = rsqrtf(var + EPS_);
    }
    __syncthreads();
    float mean = s_mean, rstd = s_rstd, gg = g[0], bb = beta[0];
    const float2 x2 = reinterpret_cast<const float2*>(x + (size_t)rowid * D_)[tid];
    float2 o;
    o.x = x2.x + gg * (a2.x - mean) * rstd + bb;
    o.y = x2.y + gg * (a2.y - mean) * rstd + bb;
    reinterpret_cast<float2*>(y + (size_t)rowid * D_)[tid] = o;
    if (ybf) {
        ushort2 ob; ob.x = f2bf(o.x); ob.y = f2bf(o.y);
        reinterpret_cast<ushort2*>(ybf + (size_t)rowid * D_)[tid] = ob;
    }
}

// ---------------------------------------------------------------------------
extern "C" void kernel_launch(void* const* d_in, const int* in_sizes, int n_in,
                              void* d_out, int out_size, void* d_ws, size_t ws_size,
                              hipStream_t stream) {
    const float* x  = (const float*)d_in[0];
    const unsigned char* mask = (const unsigned char*)d_in[1];
    const float* wq = (const float*)d_in[2];
    const float* bq = (const float*)d_in[3];
    const float* wk = (const float*)d_in[4];
    const float* bk = (const float*)d_in[5];
    const float* wv = (const float*)d_in[6];
    const float* bv = (const float*)d_in[7];
    const float* wo = (const float*)d_in[8];
    const float* bo = (const float*)d_in[9];
    const float* w1 = (const float*)d_in[10];
    const float* b1 = (const float*)d_in[11];
    const float* w2 = (const float*)d_in[12];
    const float* b2 = (const float*)d_in[13];
    const float* g1 = (const float*)d_in[14];
    const float* be1 = (const float*)d_in[15];
    const float* g2 = (const float*)d_in[16];
    const float* be2 = (const float*)d_in[17];
    float* out = (float*)d_out;
    char* base = (char*)d_ws;

    const size_t MS = (size_t)B_ * S_;                              // 8192
    unsigned short* QKb  = (unsigned short*)(base);                 // 16 MB
    unsigned short* VTg  = (unsigned short*)(base + 16777216);      // 8 MB
    unsigned short* Ob   = (unsigned short*)(base + 25165824);      // 8 MB
    unsigned short* ff1  = (unsigned short*)(base);                 // 32 MB overlay
    float*          att  = (float*)(base + 33554432);               // 16 MB
    float*          ff2  = att;                                     // overlay
    float*          y    = (float*)(base + 50331648);               // 16 MB
    unsigned short* ybf  = (unsigned short*)(base + 67108864);      // 8 MB
    unsigned short* xb   = (unsigned short*)(base + 75497472);      // 8 MB
    unsigned short* wqkvb= (unsigned short*)(base + 83886080);      // 1.5 MB
    unsigned short* wob  = (unsigned short*)(base + 85458944);      // 0.5 MB
    unsigned short* w1b  = (unsigned short*)(base + 85983232);      // 2 MB
    unsigned short* w2b  = (unsigned short*)(base + 88080384);      // 2 MB
    float*          bqkv = (float*)(base + 90177536);               // 6 KB
    float*          mb   = (float*)(base + 90183680);               // 32 KB

    dim3 blk(256);
    mask_canon_kernel<<<1, blk, 0, stream>>>(mask, mb);

    f32_to_bf16_kernel<<<(B_*S_*D_/4 + 255)/256, blk, 0, stream>>>(x, xb, B_*S_*D_/4);
    f32_to_bf16_kernel<<<(D_*D_/4 + 255)/256, blk, 0, stream>>>(wq, wqkvb,           D_*D_/4);
    f32_to_bf16_kernel<<<(D_*D_/4 + 255)/256, blk, 0, stream>>>(wk, wqkvb + D_*D_,   D_*D_/4);
    f32_to_bf16_kernel<<<(D_*D_/4 + 255)/256, blk, 0, stream>>>(wv, wqkvb + 2*D_*D_, D_*D_/4);
    f32_to_bf16_kernel<<<(D_*D_/4 + 255)/256, blk, 0, stream>>>(wo, wob, D_*D_/4);
    f32_to_bf16_kernel<<<(DFF_*D_/4 + 255)/256, blk, 0, stream>>>(w1, w1b, DFF_*D_/4);
    f32_to_bf16_kernel<<<(DFF_*D_/4 + 255)/256, blk, 0, stream>>>(w2, w2b, DFF_*D_/4);

    hipMemcpyAsync(bqkv,        bq, D_ * sizeof(float), hipMemcpyDeviceToDevice, stream);
    hipMemcpyAsync(bqkv + D_,   bk, D_ * sizeof(float), hipMemcpyDeviceToDevice, stream);
    hipMemcpyAsync(bqkv + 2*D_, bv, D_ * sizeof(float), hipMemcpyDeviceToDevice, stream);

    // fused QKV projection; V part written transposed per-head
    gemm_qkv<<<dim3(12, MS / 128), blk, 0, stream>>>(xb, wqkvb, bqkv, QKb, VTg);

    attn_mfma2<<<dim3(S_ / 128, H_, B_), blk, 0, stream>>>(QKb, VTg, mb, Ob);

    gemm_mfma<128,64,false,false><<<dim3(D_/64, MS/128), blk, 0, stream>>>(
        Ob, wob, bo, att, MS, D_, D_);

    add_ln_kernel<<<dim3((unsigned)MS), blk, 0, stream>>>(x, att, g1, be1, y, ybf);

    gemm_mfma<128,128,true,true><<<dim3(DFF_/128, MS/128), blk, 0, stream>>>(
        ybf, w1b, b1, ff1, MS, DFF_, D_);
    gemm_mfma<128,64,false,false><<<dim3(D_/64, MS/128), blk, 0, stream>>>(
        ff1, w2b, b2, ff2, MS, D_, DFF_);

    add_ln_kernel<<<dim3((unsigned)MS), blk, 0, stream>>>(y, ff2, g2, be2, out, nullptr);
}

// Round 5
// 296.759 us; speedup vs baseline: 9.0397x; 1.1224x over previous
//
#include <hip/hip_runtime.h>
#include <hip/hip_bf16.h>
#include <math.h>

#define B_ 4
#define S_ 2048
#define D_ 512
#define H_ 8
#define DK_ 64
#define DFF_ 2048
#define NEG_ (-1.0e9f)
#define EPS_ 1e-6f

typedef __attribute__((ext_vector_type(8))) short bf16x8;
typedef __attribute__((ext_vector_type(4))) float f32x4;

__device__ inline unsigned short f2bf(float f) {
    unsigned u = __float_as_uint(f);
    unsigned r = u + 0x7FFFu + ((u >> 16) & 1u);
    return (unsigned short)(r >> 16);
}

__device__ inline f32x4 mfma16(bf16x8 a, bf16x8 b, f32x4 c) {
    return __builtin_amdgcn_mfma_f32_16x16x32_bf16(a, b, c, 0, 0, 0);
}

// global -> LDS direct. LDS dest = wave-uniform base + lane*size.
__device__ inline void gload16(const void* g, void* l) {
    __builtin_amdgcn_global_load_lds(
        (const __attribute__((address_space(1))) unsigned int*)g,
        (__attribute__((address_space(3))) unsigned int*)l, 16, 0, 0);
}
__device__ inline void gload4(const void* g, void* l) {
    __builtin_amdgcn_global_load_lds(
        (const __attribute__((address_space(1))) unsigned int*)g,
        (__attribute__((address_space(3))) unsigned int*)l, 4, 0, 0);
}

// ---------------------------------------------------------------------------
// Mask canonicalization -> additive f32 bias (0 or NEG). Handles u8 / 4-byte.
// 8 blocks x 256 threads, grid-stride 2048 covers all 8192 elements.
// (r4 bug: stride-8192 loop left 3/4 of mb unwritten = poison.)
// ---------------------------------------------------------------------------
__global__ void mask_canon_kernel(const unsigned char* __restrict__ mraw,
                                  float* __restrict__ mb) {
    __shared__ int s_bad;
    int tid = threadIdx.x;
    if (tid == 0) s_bad = 0;
    __syncthreads();
    const unsigned int* w = (const unsigned int*)mraw;
    int bad = 0;
    for (int i = tid; i < (B_ * S_) / 4; i += 256) {
        unsigned int v = w[i];
        if (!(v == 0u || v == 1u || v == 0x3F800000u)) bad = 1;
    }
    if (bad) atomicOr(&s_bad, 1);
    __syncthreads();
    int i = blockIdx.x * 256 + tid;
    if (s_bad) {  // u8 layout
        for (; i < B_ * S_; i += 2048) mb[i] = mraw[i] ? NEG_ : 0.f;
    } else {      // 4-byte layout
        for (; i < B_ * S_; i += 2048) mb[i] = w[i] ? NEG_ : 0.f;
    }
}

// ---------------------------------------------------------------------------
// One-shot f32 -> bf16 conversion of x + all weights. wq scaled by 0.125
// (folds the 1/sqrt(DK) attention scale into Q; exact: power of two).
// Indexed in float4 units; segment boundaries are compile-time constants.
// ---------------------------------------------------------------------------
__global__ __launch_bounds__(256) void convert_all_kernel(
    const float* __restrict__ x,  const float* __restrict__ wq,
    const float* __restrict__ wk, const float* __restrict__ wv,
    const float* __restrict__ wo, const float* __restrict__ w1,
    const float* __restrict__ w2,
    unsigned short* __restrict__ xb, unsigned short* __restrict__ wqkvb,
    unsigned short* __restrict__ wob, unsigned short* __restrict__ w1b,
    unsigned short* __restrict__ w2b)
{
    int i = blockIdx.x * 256 + threadIdx.x;   // float4 index, total 1835008
    const float* src; unsigned short* dst; int off; float s = 1.f;
    if (i < 1048576)      { src = x;  dst = xb;             off = i;           }
    else if (i < 1114112) { src = wq; dst = wqkvb;          off = i - 1048576; s = 0.125f; }
    else if (i < 1179648) { src = wk; dst = wqkvb + 262144; off = i - 1114112; }
    else if (i < 1245184) { src = wv; dst = wqkvb + 524288; off = i - 1179648; }
    else if (i < 1310720) { src = wo; dst = wob;            off = i - 1245184; }
    else if (i < 1572864) { src = w1; dst = w1b;            off = i - 1310720; }
    else                  { src = w2; dst = w2b;            off = i - 1572864; }
    float4 v = reinterpret_cast<const float4*>(src)[off];
    ushort4 o;
    o.x = f2bf(v.x * s); o.y = f2bf(v.y * s); o.z = f2bf(v.z * s); o.w = f2bf(v.w * s);
    reinterpret_cast<ushort4*>(dst)[off] = o;
}

// ---------------------------------------------------------------------------
// Generic MFMA GEMM: C[M,N] = A[M,K](bf16) @ W[N,K](bf16)^T + bias(f32)
// ---------------------------------------------------------------------------
template<int BM, int BN, bool RELU, bool OUT_BF16>
__global__ __launch_bounds__(256) void gemm_mfma(
    const unsigned short* __restrict__ A, const unsigned short* __restrict__ W,
    const float* __restrict__ bias, void* __restrict__ Cout,
    int M, int N, int K)
{
    constexpr int FM = BM / 32;
    constexpr int FN = BN / 32;
    __shared__ unsigned short Asl[BM * 64];
    __shared__ unsigned short Bsl[BN * 64];

    const int tid = threadIdx.x;
    const int w = tid >> 6, lane = tid & 63;
    const int lr = lane & 15, lg = lane >> 4;
    const int wm = w >> 1, wn = w & 1;
    const int m0 = blockIdx.y * BM, n0 = blockIdx.x * BN;
    const int srow = lane >> 3;
    const int schunk = lane & 7;

    f32x4 acc[FM][FN] = {};

    for (int k0 = 0; k0 < K; k0 += 64) {
        __syncthreads();
        #pragma unroll
        for (int j = 0; j < BM / 32; ++j) {
            int instr = w * (BM / 32) + j;
            int row = instr * 8 + srow;
            const unsigned short* src =
                A + (size_t)(m0 + row) * K + k0 + ((schunk ^ (row & 7)) * 8);
            gload16(src, &Asl[instr * 512]);
        }
        #pragma unroll
        for (int j = 0; j < BN / 32; ++j) {
            int instr = w * (BN / 32) + j;
            int row = instr * 8 + srow;
            const unsigned short* src =
                W + (size_t)(n0 + row) * K + k0 + ((schunk ^ (row & 7)) * 8);
            gload16(src, &Bsl[instr * 512]);
        }
        __syncthreads();

        bf16x8 af[FM][2], bfr[FN][2];
        #pragma unroll
        for (int m = 0; m < FM; ++m)
            #pragma unroll
            for (int ko = 0; ko < 2; ++ko) {
                int row = wm * (FM * 16) + m * 16 + lr;
                int slot = (lg + 4 * ko) ^ (row & 7);
                af[m][ko] = *(const bf16x8*)&Asl[row * 64 + slot * 8];
            }
        #pragma unroll
        for (int n = 0; n < FN; ++n)
            #pragma unroll
            for (int ko = 0; ko < 2; ++ko) {
                int row = wn * (FN * 16) + n * 16 + lr;
                int slot = (lg + 4 * ko) ^ (row & 7);
                bfr[n][ko] = *(const bf16x8*)&Bsl[row * 64 + slot * 8];
            }
        #pragma unroll
        for (int m = 0; m < FM; ++m)
            #pragma unroll
            for (int n = 0; n < FN; ++n)
                #pragma unroll
                for (int ko = 0; ko < 2; ++ko)
                    acc[m][n] = mfma16(af[m][ko], bfr[n][ko], acc[m][n]);
    }

    #pragma unroll
    for (int n = 0; n < FN; ++n) {
        int col = n0 + wn * (FN * 16) + n * 16 + lr;
        float bv = bias[col];
        #pragma unroll
        for (int m = 0; m < FM; ++m) {
            int rowb = m0 + wm * (FM * 16) + m * 16 + lg * 4;
            #pragma unroll
            for (int r = 0; r < 4; ++r) {
                float v = acc[m][n][r] + bv;
                if (RELU) v = fmaxf(v, 0.f);
                if (OUT_BF16)
                    ((unsigned short*)Cout)[(size_t)(rowb + r) * N + col] = f2bf(v);
                else
                    ((float*)Cout)[(size_t)(rowb + r) * N + col] = v;
            }
        }
    }
}

// ---------------------------------------------------------------------------
// QKV GEMM: A[8192,512] @ Wqkv[1536,512]^T + bias (gathered from bq/bk/bv).
// Cols [0,1024) -> QKb [8192][1024] (Q|K packed; Q pre-scaled by 0.125).
// Cols [1024,1536) -> VT [b][h][d=64][s=2048] bf16, packed ushort4 along s.
// ---------------------------------------------------------------------------
__global__ __launch_bounds__(256) void gemm_qkv(
    const unsigned short* __restrict__ A, const unsigned short* __restrict__ W,
    const float* __restrict__ bqp, const float* __restrict__ bkp,
    const float* __restrict__ bvp, unsigned short* __restrict__ QKb,
    unsigned short* __restrict__ VTg)
{
    constexpr int K = 512;
    __shared__ unsigned short Asl[128 * 64];
    __shared__ unsigned short Bsl[128 * 64];

    const int tid = threadIdx.x;
    const int w = tid >> 6, lane = tid & 63;
    const int lr = lane & 15, lg = lane >> 4;
    const int wm = w >> 1, wn = w & 1;
    const int m0 = blockIdx.y * 128, n0 = blockIdx.x * 128;
    const int srow = lane >> 3;
    const int schunk = lane & 7;

    f32x4 acc[4][4] = {};

    for (int k0 = 0; k0 < K; k0 += 64) {
        __syncthreads();
        #pragma unroll
        for (int j = 0; j < 4; ++j) {
            int instr = w * 4 + j;
            int row = instr * 8 + srow;
            gload16(A + (size_t)(m0 + row) * K + k0 + ((schunk ^ (row & 7)) * 8),
                    &Asl[instr * 512]);
            gload16(W + (size_t)(n0 + row) * K + k0 + ((schunk ^ (row & 7)) * 8),
                    &Bsl[instr * 512]);
        }
        __syncthreads();

        bf16x8 af[4][2], bfr[4][2];
        #pragma unroll
        for (int m = 0; m < 4; ++m)
            #pragma unroll
            for (int ko = 0; ko < 2; ++ko) {
                int row = wm * 64 + m * 16 + lr;
                int slot = (lg + 4 * ko) ^ (row & 7);
                af[m][ko] = *(const bf16x8*)&Asl[row * 64 + slot * 8];
            }
        #pragma unroll
        for (int n = 0; n < 4; ++n)
            #pragma unroll
            for (int ko = 0; ko < 2; ++ko) {
                int row = wn * 64 + n * 16 + lr;
                int slot = (lg + 4 * ko) ^ (row & 7);
                bfr[n][ko] = *(const bf16x8*)&Bsl[row * 64 + slot * 8];
            }
        #pragma unroll
        for (int m = 0; m < 4; ++m)
            #pragma unroll
            for (int n = 0; n < 4; ++n)
                #pragma unroll
                for (int ko = 0; ko < 2; ++ko)
                    acc[m][n] = mfma16(af[m][ko], bfr[n][ko], acc[m][n]);
    }

    if (n0 < 1024) {
        #pragma unroll
        for (int n = 0; n < 4; ++n) {
            int col = n0 + wn * 64 + n * 16 + lr;
            float bv = (col < 512) ? bqp[col] * 0.125f : bkp[col - 512];
            #pragma unroll
            for (int m = 0; m < 4; ++m) {
                int rowb = m0 + wm * 64 + m * 16 + lg * 4;
                #pragma unroll
                for (int r = 0; r < 4; ++r)
                    QKb[(size_t)(rowb + r) * 1024 + col] = f2bf(acc[m][n][r] + bv);
            }
        }
    } else {
        #pragma unroll
        for (int n = 0; n < 4; ++n) {
            int col = n0 + wn * 64 + n * 16 + lr;
            int dfull = col - 1024;
            int hh = dfull >> 6, dd = dfull & 63;
            float bv = bvp[dfull];
            #pragma unroll
            for (int m = 0; m < 4; ++m) {
                int rowb = m0 + wm * 64 + m * 16 + lg * 4;
                int bb = rowb >> 11;
                int s = rowb & 2047;
                ushort4 pk;
                pk.x = f2bf(acc[m][n][0] + bv);
                pk.y = f2bf(acc[m][n][1] + bv);
                pk.z = f2bf(acc[m][n][2] + bv);
                pk.w = f2bf(acc[m][n][3] + bv);
                *(ushort4*)&VTg[(((size_t)bb * 8 + hh) * 64 + dd) * 2048 + s] = pk;
            }
        }
    }
}

// ---------------------------------------------------------------------------
// MFMA flash attention v4: QBLK=64 (wave owns 16 q-rows) for 1024 blocks =
// 4 blocks/CU TLP; bijective XCD remap so each XCD owns 4 (b,h) (KV 2MB in L2).
// Swapped QK^T; Q pre-scaled by 1/8 upstream; defer-max (THR=4).
// ---------------------------------------------------------------------------
__global__ __launch_bounds__(256, 4) void attn_mfma3(
    const unsigned short* __restrict__ QKb, const unsigned short* __restrict__ VTg,
    const float* __restrict__ mb, unsigned short* __restrict__ Ob)
{
    __shared__ unsigned short Ks[64 * 64];     // [kv][d]  swizzled 16B chunks
    __shared__ unsigned short VTs[64 * 64];    // [d][kv]  swizzled 16B chunks
    __shared__ unsigned short Ps[4 * 16 * 64]; // per-wave [q][kv] swizzled
    __shared__ float Ms[64];

    const int tid = threadIdx.x;
    const int w = tid >> 6, lane = tid & 63;
    const int lr = lane & 15, lg = lane >> 4;
    // bijective XCD remap: 1024 blocks, 8 XCDs -> each XCD gets 4 whole (b,h)
    const int flat = blockIdx.x + 32 * (blockIdx.y + 8 * blockIdx.z);
    const int nf = (flat & 7) * 128 + (flat >> 3);
    const int q0 = (nf & 31) * 64;
    const int bh = nf >> 5;
    const int h = bh & 7, b = bh >> 3;
    const int srow = lane >> 3;
    const int sc_x = (lane & 7) ^ srow;
    unsigned short* PsW = &Ps[w * 1024];

    // Q fragments: qf[ko] = Qscaled[q = q0+w*16+lr][d = lg*8+32*ko ..]
    bf16x8 qf[2];
    #pragma unroll
    for (int ko = 0; ko < 2; ++ko)
        qf[ko] = *(const bf16x8*)(QKb +
            (size_t)(b * S_ + q0 + w * 16 + lr) * 1024 + h * 64 + ko * 32 + lg * 8);

    f32x4 od[4] = {};
    float m_run = -INFINITY;
    float l_run = 0.f;

    for (int kv0 = 0; kv0 < S_; kv0 += 64) {
        __syncthreads();
        #pragma unroll
        for (int j = 0; j < 2; ++j) {
            int rl = w * 16 + j * 8 + srow;
            gload16(QKb + (size_t)(b * S_ + kv0 + rl) * 1024 + 512 + h * 64 + sc_x * 8,
                    &Ks[(w * 2 + j) * 512]);
            gload16(VTg + ((size_t)bh * 64 + rl) * 2048 + kv0 + sc_x * 8,
                    &VTs[(w * 2 + j) * 512]);
        }
        if (w == 0) gload4(mb + (size_t)b * S_ + kv0 + lane, Ms);
        __syncthreads();

        // swapped QK^T: st[n] reg r = S^T[kv=16n+4lg+r][q=lr] (Q pre-scaled)
        f32x4 st[4] = {};
        #pragma unroll
        for (int ko = 0; ko < 2; ++ko)
            #pragma unroll
            for (int n = 0; n < 4; ++n) {
                bf16x8 kf = *(const bf16x8*)
                    &Ks[(n * 16 + lr) * 64 + (((lg + 4 * ko) ^ (lr & 7)) * 8)];
                st[n] = mfma16(kf, qf[ko], st[n]);
            }

        float mtp = -INFINITY;
        #pragma unroll
        for (int n = 0; n < 4; ++n) {
            f32x4 mbr = *(const f32x4*)&Ms[n * 16 + lg * 4];
            #pragma unroll
            for (int r = 0; r < 4; ++r) {
                float v = st[n][r] + mbr[r];
                st[n][r] = v;
                mtp = fmaxf(mtp, v);
            }
        }

        // defer-max: rescale only if some partial max exceeds m_run + 4
        if (__any(mtp > m_run + 4.f)) {
            float mt = mtp;
            mt = fmaxf(mt, __shfl_xor(mt, 16));
            mt = fmaxf(mt, __shfl_xor(mt, 32));
            float mnew = fmaxf(m_run, mt);
            float scl = __expf(m_run - mnew);
            m_run = mnew;
            l_run *= scl;
            #pragma unroll
            for (int r = 0; r < 4; ++r) {
                float sr = __shfl(scl, lg * 4 + r);
                #pragma unroll
                for (int nd = 0; nd < 4; ++nd) od[nd][r] *= sr;
            }
        }

        float psum = 0.f;
        #pragma unroll
        for (int n = 0; n < 4; ++n) {
            float p0 = __expf(st[n][0] - m_run);
            float p1 = __expf(st[n][1] - m_run);
            float p2 = __expf(st[n][2] - m_run);
            float p3 = __expf(st[n][3] - m_run);
            psum += (p0 + p1) + (p2 + p3);
            ushort4 pk;
            pk.x = f2bf(p0); pk.y = f2bf(p1); pk.z = f2bf(p2); pk.w = f2bf(p3);
            int chunk = (2 * n + (lg >> 1)) ^ (lr & 7);
            *(ushort4*)&PsW[lr * 64 + chunk * 8 + (lg & 1) * 4] = pk;
        }
        psum += __shfl_xor(psum, 16);
        psum += __shfl_xor(psum, 32);
        l_run += psum;

        // PV: od[nd] += P[q][kv] * V^T[d][kv]
        #pragma unroll
        for (int ko = 0; ko < 2; ++ko) {
            int slotx = ((lg + 4 * ko) ^ (lr & 7)) * 8;
            bf16x8 pa = *(const bf16x8*)&PsW[lr * 64 + slotx];
            #pragma unroll
            for (int nd = 0; nd < 4; ++nd) {
                bf16x8 vf = *(const bf16x8*)&VTs[(nd * 16 + lr) * 64 + slotx];
                od[nd] = mfma16(pa, vf, od[nd]);
            }
        }
    }

    float linv = 1.f / l_run;
    #pragma unroll
    for (int r = 0; r < 4; ++r) {
        float iv = __shfl(linv, lg * 4 + r);
        size_t row = (size_t)(b * S_ + q0 + w * 16 + lg * 4 + r);
        #pragma unroll
        for (int nd = 0; nd < 4; ++nd)
            Ob[row * 512 + h * 64 + nd * 16 + lr] = f2bf(od[nd][r] * iv);
    }
}

// ---------------------------------------------------------------------------
// y = x + gamma*(a-mean)/sqrt(var_ddof1+eps) + beta ; optional bf16 copy of y
// ---------------------------------------------------------------------------
__global__ __launch_bounds__(256) void add_ln_kernel(
    const float* __restrict__ x, const float* __restrict__ a,
    const float* __restrict__ g, const float* __restrict__ beta,
    float* __restrict__ y, unsigned short* __restrict__ ybf)
{
    int rowid = blockIdx.x;
    int tid = threadIdx.x;
    const float2 a2 = reinterpret_cast<const float2*>(a + (size_t)rowid * D_)[tid];
    float s = a2.x + a2.y;
    float ss = a2.x * a2.x + a2.y * a2.y;
    #pragma unroll
    for (int off = 32; off > 0; off >>= 1) {
        s += __shfl_down(s, off);
        ss += __shfl_down(ss, off);
    }
    __shared__ float ws_s[4], ws_ss[4];
    __shared__ float s_mean, s_rstd;
    int wave = tid >> 6, lane = tid & 63;
    if (lane == 0) { ws_s[wave] = s; ws_ss[wave] = ss; }
    __syncthreads();
    if (tid == 0) {
        float st = ws_s[0] + ws_s[1] + ws_s[2] + ws_s[3];
        float sst = ws_ss[0] + ws_ss[1] + ws_ss[2] + ws_ss[3];
        float mean = st / (float)D_;
        float var = (sst - (float)D_ * mean * mean) / (float)(D_ - 1);
        s_mean = mean;
        s_rstd = rsqrtf(var + EPS_);
    }
    __syncthreads();
    float mean = s_mean, rstd = s_rstd, gg = g[0], bb = beta[0];
    const float2 x2 = reinterpret_cast<const float2*>(x + (size_t)rowid * D_)[tid];
    float2 o;
    o.x = x2.x + gg * (a2.x - mean) * rstd + bb;
    o.y = x2.y + gg * (a2.y - mean) * rstd + bb;
    reinterpret_cast<float2*>(y + (size_t)rowid * D_)[tid] = o;
    if (ybf) {
        ushort2 ob; ob.x = f2bf(o.x); ob.y = f2bf(o.y);
        reinterpret_cast<ushort2*>(ybf + (size_t)rowid * D_)[tid] = ob;
    }
}

// ---------------------------------------------------------------------------
extern "C" void kernel_launch(void* const* d_in, const int* in_sizes, int n_in,
                              void* d_out, int out_size, void* d_ws, size_t ws_size,
                              hipStream_t stream) {
    const float* x  = (const float*)d_in[0];
    const unsigned char* mask = (const unsigned char*)d_in[1];
    const float* wq = (const float*)d_in[2];
    const float* bq = (const float*)d_in[3];
    const float* wk = (const float*)d_in[4];
    const float* bk = (const float*)d_in[5];
    const float* wv = (const float*)d_in[6];
    const float* bv = (const float*)d_in[7];
    const float* wo = (const float*)d_in[8];
    const float* bo = (const float*)d_in[9];
    const float* w1 = (const float*)d_in[10];
    const float* b1 = (const float*)d_in[11];
    const float* w2 = (const float*)d_in[12];
    const float* b2 = (const float*)d_in[13];
    const float* g1 = (const float*)d_in[14];
    const float* be1 = (const float*)d_in[15];
    const float* g2 = (const float*)d_in[16];
    const float* be2 = (const float*)d_in[17];
    float* out = (float*)d_out;
    char* base = (char*)d_ws;

    const size_t MS = (size_t)B_ * S_;                              // 8192
    unsigned short* QKb  = (unsigned short*)(base);                 // 16 MB
    unsigned short* VTg  = (unsigned short*)(base + 16777216);      // 8 MB
    unsigned short* Ob   = (unsigned short*)(base + 25165824);      // 8 MB
    unsigned short* ff1  = (unsigned short*)(base);                 // 32 MB overlay
    float*          att  = (float*)(base + 33554432);               // 16 MB
    float*          ff2  = att;                                     // overlay
    float*          y    = (float*)(base + 50331648);               // 16 MB
    unsigned short* ybf  = (unsigned short*)(base + 67108864);      // 8 MB
    unsigned short* xb   = (unsigned short*)(base + 75497472);      // 8 MB
    unsigned short* wqkvb= (unsigned short*)(base + 83886080);      // 1.5 MB
    unsigned short* wob  = (unsigned short*)(base + 85458944);      // 0.5 MB
    unsigned short* w1b  = (unsigned short*)(base + 85983232);      // 2 MB
    unsigned short* w2b  = (unsigned short*)(base + 88080384);      // 2 MB
    float*          mbv  = (float*)(base + 90183680);               // 32 KB

    dim3 blk(256);
    mask_canon_kernel<<<8, blk, 0, stream>>>(mask, mbv);

    convert_all_kernel<<<7168, blk, 0, stream>>>(
        x, wq, wk, wv, wo, w1, w2, xb, wqkvb, wob, w1b, w2b);

    // fused QKV projection; Q pre-scaled, V written transposed per-head
    gemm_qkv<<<dim3(12, MS / 128), blk, 0, stream>>>(
        xb, wqkvb, bq, bk, bv, QKb, VTg);

    attn_mfma3<<<dim3(S_ / 64, H_, B_), blk, 0, stream>>>(QKb, VTg, mbv, Ob);

    gemm_mfma<128,64,false,false><<<dim3(D_/64, MS/128), blk, 0, stream>>>(
        Ob, wob, bo, att, MS, D_, D_);

    add_ln_kernel<<<dim3((unsigned)MS), blk, 0, stream>>>(x, att, g1, be1, y, ybf);

    gemm_mfma<128,128,true,true><<<dim3(DFF_/128, MS/128), blk, 0, stream>>>(
        ybf, w1b, b1, ff1, MS, DFF_, D_);
    gemm_mfma<128,64,false,false><<<dim3(D_/64, MS/128), blk, 0, stream>>>(
        ff1, w2b, b2, ff2, MS, D_, DFF_);

    add_ln_kernel<<<dim3((unsigned)MS), blk, 0, stream>>>(y, ff2, g2, be2, out, nullptr);
}